// Round 1
// baseline (221.909 us; speedup 1.0000x reference)
//
#include <hip/hip_runtime.h>

#define NB 2048
#define NS 1024
#define NL 32

static __device__ __forceinline__ float fexp2(float x) {
#if __has_builtin(__builtin_amdgcn_exp2f)
  return __builtin_amdgcn_exp2f(x);
#else
  float r; asm("v_exp_f32 %0, %1" : "=v"(r) : "v"(x)); return r;
#endif
}
static __device__ __forceinline__ float flog2(float x) {
#if __has_builtin(__builtin_amdgcn_logf)
  return __builtin_amdgcn_logf(x);
#else
  float r; asm("v_log_f32 %0, %1" : "=v"(r) : "v"(x)); return r;
#endif
}

template<int K>
static __device__ __forceinline__ int roti(int x) {
  if constexpr (K == 0) return x;
  else return __builtin_amdgcn_update_dpp(0, x, 0x120 | K, 0xf, 0xf, true); // row_ror:K
}
template<int K>
static __device__ __forceinline__ float rotf(float x) {
  return __int_as_float(roti<K>(__float_as_int(x)));
}

__global__ void zero_out_k(float* out) {
  if (threadIdx.x < 2) out[threadIdx.x] = 0.0f;
}

__global__ __launch_bounds__(64, 2)
void crf_fwd(const float* __restrict__ scores, const float* __restrict__ trans,
             const int* __restrict__ lens, const int* __restrict__ tags,
             float* __restrict__ out)
{
  constexpr float LOG2E = 1.4426950408889634f;
  constexpr float LN2   = 0.6931471805599453f;
  __shared__ float Tld[NL * NL];        // transition * log2e
  __shared__ float Emt[2][32 * NL];     // emit chunk double-buffer (32 rows)

  const int b    = blockIdx.x;
  const int lane = threadIdx.x;
  const int len  = lens[b];
  const int r = lane >> 4, c = lane & 15;
  const int ibase = (r & 1) << 4;                         // i-half this row reduces
  const int jout  = c + (((r == 1) || (r == 2)) ? 16 : 0); // output label this lane computes
  const int jheld = c + ibase;                             // label whose alpha/p this lane holds
  const float* sb = scores + (size_t)b * (NS * NL);

#define STAGE(BUFI, T0) do { \
    const float* gsrc_ = sb + (size_t)(T0) * NL; \
    _Pragma("unroll") \
    for (int k_ = 0; k_ < 4; ++k_) \
      __builtin_amdgcn_global_load_lds( \
        (const __attribute__((address_space(1))) void*)(gsrc_ + k_ * 256 + lane * 4), \
        (__attribute__((address_space(3))) void*)(&Emt[BUFI][k_ * 256]), 16, 0, 0); \
  } while (0)

  // issue emit staging early (latency hidden under setup)
  STAGE(0, 0);
  if (len > 32) STAGE(1, 32);

  // transition -> LDS (scaled to base-2 domain)
  #pragma unroll
  for (int k = 0; k < NL * NL; k += 64) Tld[k + lane] = trans[k + lane] * LOG2E;

  // E registers in DPP-arrival order, self-calibrated: feed lane indices through
  // the same rotate so correctness is independent of exact ror semantics.
  float E[16];
#define CAL(K) E[K] = fexp2(Tld[roti<K>(ibase + c) * NL + jout]);
  CAL(0)  CAL(1)  CAL(2)  CAL(3)  CAL(4)  CAL(5)  CAL(6)  CAL(7)
  CAL(8)  CAL(9)  CAL(10) CAL(11) CAL(12) CAL(13) CAL(14) CAL(15)
#undef CAL
  const float Tend = Tld[jheld * NL + 30];  // T~[j][end]

  // init: alpha~_j = T~[start=31][j] + log2e * emit[0][j]
  float alpha = Tld[31 * NL + jheld];
  asm volatile("s_waitcnt vmcnt(0)" ::: "memory");
  alpha = fmaf(Emt[0][jheld], LOG2E, alpha);

  float e_next = (len > 1) ? Emt[0][NL + jout] : 0.0f;
  int buf = 0;

  for (int t = 1; t < len; ++t) {
    const float e = e_next;
    const float m = __int_as_float(__builtin_amdgcn_readfirstlane(__float_as_int(alpha)));
    const float p = fexp2(alpha - m);
    float a0 = p * E[0];
    float a1 = rotf<1>(p) * E[1];
    float a2 = rotf<2>(p) * E[2];
    float a3 = rotf<3>(p) * E[3];
    a0 = fmaf(rotf<4>(p),  E[4],  a0);
    a1 = fmaf(rotf<5>(p),  E[5],  a1);
    a2 = fmaf(rotf<6>(p),  E[6],  a2);
    a3 = fmaf(rotf<7>(p),  E[7],  a3);
    a0 = fmaf(rotf<8>(p),  E[8],  a0);
    a1 = fmaf(rotf<9>(p),  E[9],  a1);
    a2 = fmaf(rotf<10>(p), E[10], a2);
    a3 = fmaf(rotf<11>(p), E[11], a3);
    a0 = fmaf(rotf<12>(p), E[12], a0);
    a1 = fmaf(rotf<13>(p), E[13], a1);
    a2 = fmaf(rotf<14>(p), E[14], a2);
    a3 = fmaf(rotf<15>(p), E[15], a3);
    float s = (a0 + a1) + (a2 + a3);
    s += __shfl_xor(s, 48);                       // combine i-halves -> full s_jout
    const float anew = fmaf(e, LOG2E, m + flog2(s));
    const float sw = __shfl_xor(anew, 16);        // rows 2<->3 exchange
    alpha = (lane < 32) ? anew : sw;              // now holds alpha_jheld

    const int tn = t + 1;
    if (tn < len) {
      if (tn & 31) {
        e_next = Emt[buf][(tn & 31) * NL + jout];
      } else {
        asm volatile("s_waitcnt vmcnt(0)" ::: "memory");
        buf ^= 1;
        e_next = Emt[buf][jout];
        if (tn + 32 < len) STAGE(buf ^ 1, tn + 32);
      }
    }
  }

  // unlabeled: ln2 * logsumexp2_j(alpha~_j + T~[j][end]); each j duplicated 2x -> subtract 1
  float v = alpha + Tend;
  float mm = v;
  #pragma unroll
  for (int w = 32; w; w >>= 1) mm = fmaxf(mm, __shfl_xor(mm, w));
  float ss = fexp2(v - mm);
  #pragma unroll
  for (int w = 32; w; w >>= 1) ss += __shfl_xor(ss, w);
  if (lane == 0) atomicAdd(out + 0, LN2 * (mm + flog2(ss) - 1.0f));

  // labeled score (scaled domain, *ln2 at end)
  const int* tb = tags + (size_t)b * NS;
  float lab = 0.0f;
  if (lane == 0) {
    const int tg0 = tb[0];
    lab += Tld[31 * NL + tg0] + LOG2E * sb[tg0];   // begin
    const int tgl = tb[len - 1];
    lab += Tld[tgl * NL + 30];                     // end
  }
  for (int t = 1 + lane; t < len; t += 64) {
    const int tp = tb[t - 1];
    const int tg = tb[t];
    lab += Tld[tp * NL + tg] + LOG2E * sb[(size_t)t * NL + tg];
  }
  #pragma unroll
  for (int w = 32; w; w >>= 1) lab += __shfl_xor(lab, w);
  if (lane == 0) atomicAdd(out + 1, LN2 * lab);
#undef STAGE
}

extern "C" void kernel_launch(void* const* d_in, const int* in_sizes, int n_in,
                              void* d_out, int out_size, void* d_ws, size_t ws_size,
                              hipStream_t stream) {
  const float* scores = (const float*)d_in[0];
  const float* trans  = (const float*)d_in[1];
  const int*   lens   = (const int*)d_in[2];
  const int*   tags   = (const int*)d_in[3];
  float* out = (float*)d_out;

  zero_out_k<<<1, 64, 0, stream>>>(out);
  crf_fwd<<<NB, 64, 0, stream>>>(scores, trans, lens, tags, out);
}

// Round 7
// 200.020 us; speedup vs baseline: 1.1094x; 1.1094x over previous
//
#include <hip/hip_runtime.h>

#define NB 2048
#define NS 1024
#define NL 32

static __device__ __forceinline__ float fexp2(float x) {
#if __has_builtin(__builtin_amdgcn_exp2f)
  return __builtin_amdgcn_exp2f(x);
#else
  float r; asm("v_exp_f32 %0, %1" : "=v"(r) : "v"(x)); return r;
#endif
}
static __device__ __forceinline__ float flog2(float x) {
#if __has_builtin(__builtin_amdgcn_logf)
  return __builtin_amdgcn_logf(x);
#else
  float r; asm("v_log_f32 %0, %1" : "=v"(r) : "v"(x)); return r;
#endif
}

template<int K>
static __device__ __forceinline__ int roti(int x) {
  if constexpr (K == 0) return x;
  else return __builtin_amdgcn_update_dpp(0, x, 0x120 | K, 0xf, 0xf, true); // row_ror:K
}
template<int K>
static __device__ __forceinline__ float rotf(float x) {
  return __int_as_float(roti<K>(__float_as_int(x)));
}

// sum of part over lane pairs l, l^XOR — via __shfl_xor (validated in R1).
template<int XOR>
static __device__ __forceinline__ float combine_swap(float part) {
  return part + __shfl_xor(part, XOR);
}

// 16-term rotate/FMA tree: sum_k rot_k(p) * E[k], 4 chains of depth 4
static __device__ __forceinline__ float tree16(float p, const float* E) {
  float a0 = p * E[0];
  float a1 = rotf<1>(p) * E[1];
  float a2 = rotf<2>(p) * E[2];
  float a3 = rotf<3>(p) * E[3];
  a0 = fmaf(rotf<4>(p),  E[4],  a0);
  a1 = fmaf(rotf<5>(p),  E[5],  a1);
  a2 = fmaf(rotf<6>(p),  E[6],  a2);
  a3 = fmaf(rotf<7>(p),  E[7],  a3);
  a0 = fmaf(rotf<8>(p),  E[8],  a0);
  a1 = fmaf(rotf<9>(p),  E[9],  a1);
  a2 = fmaf(rotf<10>(p), E[10], a2);
  a3 = fmaf(rotf<11>(p), E[11], a3);
  a0 = fmaf(rotf<12>(p), E[12], a0);
  a1 = fmaf(rotf<13>(p), E[13], a1);
  a2 = fmaf(rotf<14>(p), E[14], a2);
  a3 = fmaf(rotf<15>(p), E[15], a3);
  return (a0 + a1) + (a2 + a3);
}

__global__ void zero_out_k(float* out) {
  if (threadIdx.x < 2) out[threadIdx.x] = 0.0f;
}

__global__ __launch_bounds__(64, 2)
void crf_fwd(const float* __restrict__ scores, const float* __restrict__ trans,
             const int* __restrict__ lens, const int* __restrict__ tags,
             float* __restrict__ out)
{
  constexpr float LOG2E = 1.4426950408889634f;
  constexpr float LN2   = 0.6931471805599453f;
  __shared__ float Tld[NL * NL];        // transition * log2e
  __shared__ float Emt[2][32 * NL];     // emit chunk double-buffer (32 rows)

  const int b    = blockIdx.x;
  const int lane = threadIdx.x;
  const int len  = lens[b];
  const int r = lane >> 4, c = lane & 15;
  const int labA = c + ((r & 1) << 4);         // label held in layout A (rows lo,hi,lo,hi)
  const int labB = c + (((r >> 1) & 1) << 4);  // label held in layout B (rows lo,lo,hi,hi)
  const float* sb = scores + (size_t)b * (NS * NL);

#define STAGE(BUFI, T0) do { \
    const float* gsrc_ = sb + (size_t)(T0) * NL; \
    _Pragma("unroll") \
    for (int k_ = 0; k_ < 4; ++k_) \
      __builtin_amdgcn_global_load_lds( \
        (const __attribute__((address_space(1))) void*)(gsrc_ + k_ * 256 + lane * 4), \
        (__attribute__((address_space(3))) void*)(&Emt[BUFI][k_ * 256]), 16, 0, 0); \
  } while (0)

  STAGE(0, 0);
  if (len > 32) STAGE(1, 32);

  #pragma unroll
  for (int k = 0; k < NL * NL; k += 64) Tld[k + lane] = trans[k + lane] * LOG2E;

  // E sets for both layouts, rotation-arrival order self-calibrated.
  // Step A: lane holds p_labA, computes output label labB. Step B: vice versa.
  float EA[16], EB[16];
#define CALA(K) EA[K] = fexp2(Tld[roti<K>(labA) * NL + labB]);
#define CALB(K) EB[K] = fexp2(Tld[roti<K>(labB) * NL + labA]);
  CALA(0)  CALA(1)  CALA(2)  CALA(3)  CALA(4)  CALA(5)  CALA(6)  CALA(7)
  CALA(8)  CALA(9)  CALA(10) CALA(11) CALA(12) CALA(13) CALA(14) CALA(15)
  CALB(0)  CALB(1)  CALB(2)  CALB(3)  CALB(4)  CALB(5)  CALB(6)  CALB(7)
  CALB(8)  CALB(9)  CALB(10) CALB(11) CALB(12) CALB(13) CALB(14) CALB(15)
#undef CALA
#undef CALB

  // init (layout A): alpha~0_j = T~[start=31][j] + log2e*emit0[j]; u = 2^(a0 - ls)
  float a0 = Tld[31 * NL + labA];
  asm volatile("s_waitcnt vmcnt(0)" ::: "memory");
  a0 = fmaf(Emt[0][labA], LOG2E, a0);
  float ls = __int_as_float(__builtin_amdgcn_readfirstlane(__float_as_int(a0)));
  float u = fexp2(a0 - ls);

  // emit lookahead: eA for odd times (A-steps, label labB), eB for even times (label labA)
  float eA = (len > 1) ? Emt[0][1 * NL + labB] : 0.0f;
  float eB = (len > 2) ? Emt[0][2 * NL + labA] : 0.0f;
  int buf = 0;
  bool endB = false;

  int t = 1;
  while (t + 1 < len) {
    if ((t & 3) == 1) {  // renorm every 4 steps: scale by 2^-exp(u_lane0)
      const int eb = __builtin_amdgcn_readfirstlane(__float_as_int(u));
      const int ex = (eb >> 23) - 127;
      ls += (float)ex;
      u *= __int_as_float((127 - ex) << 23);
    }
    const float wA = fexp2(eA * LOG2E);
    const float wB = fexp2(eB * LOG2E);
    // prefetch next pair's emits (consumed ~2 steps later)
    {
      const int tn = t + 2;                    // odd: never row 0
      if (tn < len) eA = Emt[buf][(tn & 31) * NL + labB];
    }
    {
      const int tn = t + 3;                    // even: handles chunk boundary
      if (tn < len) {
        const int row = tn & 31;
        if (row) {
          eB = Emt[buf][row * NL + labA];
        } else {
          asm volatile("s_waitcnt vmcnt(0) lgkmcnt(0)" ::: "memory");
          buf ^= 1;
          eB = Emt[buf][labA];
          if (tn + 32 < len) STAGE(buf ^ 1, tn + 32);
        }
      }
    }
    // step A (time t):   combine partner ^16, layout A -> B
    u = combine_swap<16>(tree16(u, EA)) * wA;
    // step B (time t+1): combine partner ^32, layout B -> A
    u = combine_swap<32>(tree16(u, EB)) * wB;
    t += 2;
  }
  if (t < len) {  // leftover single A-step; state ends in layout B
    if ((t & 3) == 1) {
      const int eb = __builtin_amdgcn_readfirstlane(__float_as_int(u));
      const int ex = (eb >> 23) - 127;
      ls += (float)ex;
      u *= __int_as_float((127 - ex) << 23);
    }
    const float wA = fexp2(eA * LOG2E);
    u = combine_swap<16>(tree16(u, EA)) * wA;
    endB = true;
  }

  // unlabeled: ln2 * logsumexp2_j(alpha~_j + T~[j][end]); each j appears 2x -> -1
  const int elab = endB ? labB : labA;
  const float alpha = ls + flog2(u);
  float v = alpha + Tld[elab * NL + 30];
  float mm = v;
  #pragma unroll
  for (int w = 32; w; w >>= 1) mm = fmaxf(mm, __shfl_xor(mm, w));
  float ss = fexp2(v - mm);
  #pragma unroll
  for (int w = 32; w; w >>= 1) ss += __shfl_xor(ss, w);
  if (lane == 0) atomicAdd(out + 0, LN2 * (mm + flog2(ss) - 1.0f));

  // labeled score (scaled domain, *ln2 at end)
  const int* tb = tags + (size_t)b * NS;
  float lab = 0.0f;
  if (lane == 0) {
    const int tg0 = tb[0];
    lab += Tld[31 * NL + tg0] + LOG2E * sb[tg0];   // begin
    const int tgl = tb[len - 1];
    lab += Tld[tgl * NL + 30];                     // end
  }
  for (int t2 = 1 + lane; t2 < len; t2 += 64) {
    const int tp = tb[t2 - 1];
    const int tg = tb[t2];
    lab += Tld[tp * NL + tg] + LOG2E * sb[(size_t)t2 * NL + tg];
  }
  #pragma unroll
  for (int w = 32; w; w >>= 1) lab += __shfl_xor(lab, w);
  if (lane == 0) atomicAdd(out + 1, LN2 * lab);
#undef STAGE
}

extern "C" void kernel_launch(void* const* d_in, const int* in_sizes, int n_in,
                              void* d_out, int out_size, void* d_ws, size_t ws_size,
                              hipStream_t stream) {
  const float* scores = (const float*)d_in[0];
  const float* trans  = (const float*)d_in[1];
  const int*   lens   = (const int*)d_in[2];
  const int*   tags   = (const int*)d_in[3];
  float* out = (float*)d_out;

  zero_out_k<<<1, 64, 0, stream>>>(out);
  crf_fwd<<<NB, 64, 0, stream>>>(scores, trans, lens, tags, out);
}

// Round 9
// 192.748 us; speedup vs baseline: 1.1513x; 1.0377x over previous
//
#include <hip/hip_runtime.h>

#define NB 2048
#define NS 1024
#define NL 32

static __device__ __forceinline__ float fexp2(float x) {
#if __has_builtin(__builtin_amdgcn_exp2f)
  return __builtin_amdgcn_exp2f(x);
#else
  float r; asm("v_exp_f32 %0, %1" : "=v"(r) : "v"(x)); return r;
#endif
}
static __device__ __forceinline__ float flog2(float x) {
#if __has_builtin(__builtin_amdgcn_logf)
  return __builtin_amdgcn_logf(x);
#else
  float r; asm("v_log_f32 %0, %1" : "=v"(r) : "v"(x)); return r;
#endif
}

template<int K>
static __device__ __forceinline__ int roti(int x) {
  if constexpr (K == 0) return x;
  else return __builtin_amdgcn_update_dpp(0, x, 0x120 | K, 0xf, 0xf, true); // row_ror:K
}
template<int K>
static __device__ __forceinline__ float rotf(float x) {
  return __int_as_float(roti<K>(__float_as_int(x)));
}

// part + part[lane^XOR] via gfx950 permlane-swap BUILTINS (compiler handles
// hazards + regalloc; returns BOTH post-swap words so r0+r1 is the pair sum
// under any swap-direction convention). Fallback: shfl_xor (correct, slower).
template<int XOR>
static __device__ __forceinline__ float combine_swap(float part) {
  if constexpr (XOR == 16) {
#if __has_builtin(__builtin_amdgcn_permlane16_swap)
    auto rr = __builtin_amdgcn_permlane16_swap(__float_as_uint(part), __float_as_uint(part), false, false);
    return __uint_as_float(rr[0]) + __uint_as_float(rr[1]);
#else
    return part + __shfl_xor(part, 16);
#endif
  } else {
#if __has_builtin(__builtin_amdgcn_permlane32_swap)
    auto rr = __builtin_amdgcn_permlane32_swap(__float_as_uint(part), __float_as_uint(part), false, false);
    return __uint_as_float(rr[0]) + __uint_as_float(rr[1]);
#else
    return part + __shfl_xor(part, 32);
#endif
  }
}

// 16-term rotate/FMA tree: sum_k rot_k(p) * E[k], 4 chains of depth 4
static __device__ __forceinline__ float tree16(float p, const float* E) {
  float a0 = p * E[0];
  float a1 = rotf<1>(p) * E[1];
  float a2 = rotf<2>(p) * E[2];
  float a3 = rotf<3>(p) * E[3];
  a0 = fmaf(rotf<4>(p),  E[4],  a0);
  a1 = fmaf(rotf<5>(p),  E[5],  a1);
  a2 = fmaf(rotf<6>(p),  E[6],  a2);
  a3 = fmaf(rotf<7>(p),  E[7],  a3);
  a0 = fmaf(rotf<8>(p),  E[8],  a0);
  a1 = fmaf(rotf<9>(p),  E[9],  a1);
  a2 = fmaf(rotf<10>(p), E[10], a2);
  a3 = fmaf(rotf<11>(p), E[11], a3);
  a0 = fmaf(rotf<12>(p), E[12], a0);
  a1 = fmaf(rotf<13>(p), E[13], a1);
  a2 = fmaf(rotf<14>(p), E[14], a2);
  a3 = fmaf(rotf<15>(p), E[15], a3);
  return (a0 + a1) + (a2 + a3);
}

__global__ void zero_out_k(float* out) {
  if (threadIdx.x < 2) out[threadIdx.x] = 0.0f;
}

__global__ __launch_bounds__(64, 2)
void crf_fwd(const float* __restrict__ scores, const float* __restrict__ trans,
             const int* __restrict__ lens, const int* __restrict__ tags,
             float* __restrict__ out)
{
  constexpr float LOG2E = 1.4426950408889634f;
  constexpr float LN2   = 0.6931471805599453f;
  __shared__ float Tld[NL * NL];        // transition * log2e
  __shared__ float Emt[2][32 * NL];     // emit chunk double-buffer (32 rows)

  const int b    = blockIdx.x;
  const int lane = threadIdx.x;
  const int len  = lens[b];
  const int r = lane >> 4, c = lane & 15;
  const int labA = c + ((r & 1) << 4);         // label held in layout A (rows lo,hi,lo,hi)
  const int labB = c + (((r >> 1) & 1) << 4);  // label held in layout B (rows lo,lo,hi,hi)
  const float* sb = scores + (size_t)b * (NS * NL);

#define STAGE(BUFI, T0) do { \
    const float* gsrc_ = sb + (size_t)(T0) * NL; \
    _Pragma("unroll") \
    for (int k_ = 0; k_ < 4; ++k_) \
      __builtin_amdgcn_global_load_lds( \
        (const __attribute__((address_space(1))) void*)(gsrc_ + k_ * 256 + lane * 4), \
        (__attribute__((address_space(3))) void*)(&Emt[BUFI][k_ * 256]), 16, 0, 0); \
  } while (0)

  STAGE(0, 0);
  if (len > 32) STAGE(1, 32);

  #pragma unroll
  for (int k = 0; k < NL * NL; k += 64) Tld[k + lane] = trans[k + lane] * LOG2E;

  // E sets for both layouts, rotation-arrival order self-calibrated.
  // Step A: lane holds p_labA, computes output label labB. Step B: vice versa.
  float EA[16], EB[16];
#define CALA(K) EA[K] = fexp2(Tld[roti<K>(labA) * NL + labB]);
#define CALB(K) EB[K] = fexp2(Tld[roti<K>(labB) * NL + labA]);
  CALA(0)  CALA(1)  CALA(2)  CALA(3)  CALA(4)  CALA(5)  CALA(6)  CALA(7)
  CALA(8)  CALA(9)  CALA(10) CALA(11) CALA(12) CALA(13) CALA(14) CALA(15)
  CALB(0)  CALB(1)  CALB(2)  CALB(3)  CALB(4)  CALB(5)  CALB(6)  CALB(7)
  CALB(8)  CALB(9)  CALB(10) CALB(11) CALB(12) CALB(13) CALB(14) CALB(15)
#undef CALA
#undef CALB

  // init (layout A): alpha~0_j = T~[start=31][j] + log2e*emit0[j]; u = 2^(a0 - ls)
  float a0 = Tld[31 * NL + labA];
  asm volatile("s_waitcnt vmcnt(0)" ::: "memory");
  a0 = fmaf(Emt[0][labA], LOG2E, a0);
  float ls = __int_as_float(__builtin_amdgcn_readfirstlane(__float_as_int(a0)));
  float u = fexp2(a0 - ls);

  // emit lookahead: eA for odd times (A-steps, label labB), eB for even times (label labA)
  float eA = (len > 1) ? Emt[0][1 * NL + labB] : 0.0f;
  float eB = (len > 2) ? Emt[0][2 * NL + labA] : 0.0f;
  int buf = 0;
  bool endB = false;

  int t = 1;
  while (t + 1 < len) {
    if ((t & 3) == 1) {  // renorm every 4 steps: scale by 2^-exp(u_lane0)
      const int eb = __builtin_amdgcn_readfirstlane(__float_as_int(u));
      const int ex = (eb >> 23) - 127;
      ls += (float)ex;
      u *= __int_as_float((127 - ex) << 23);
    }
    const float wA = fexp2(eA * LOG2E);
    const float wB = fexp2(eB * LOG2E);
    // prefetch next pair's emits (consumed ~2 steps later)
    {
      const int tn = t + 2;                    // odd: never row 0
      if (tn < len) eA = Emt[buf][(tn & 31) * NL + labB];
    }
    {
      const int tn = t + 3;                    // even: handles chunk boundary
      if (tn < len) {
        const int row = tn & 31;
        if (row) {
          eB = Emt[buf][row * NL + labA];
        } else {
          asm volatile("s_waitcnt vmcnt(0) lgkmcnt(0)" ::: "memory");
          buf ^= 1;
          eB = Emt[buf][labA];
          if (tn + 32 < len) STAGE(buf ^ 1, tn + 32);
        }
      }
    }
    // step A (time t):   combine partner ^16, layout A -> B
    u = combine_swap<16>(tree16(u, EA)) * wA;
    // step B (time t+1): combine partner ^32, layout B -> A
    u = combine_swap<32>(tree16(u, EB)) * wB;
    t += 2;
  }
  if (t < len) {  // leftover single A-step; state ends in layout B
    if ((t & 3) == 1) {
      const int eb = __builtin_amdgcn_readfirstlane(__float_as_int(u));
      const int ex = (eb >> 23) - 127;
      ls += (float)ex;
      u *= __int_as_float((127 - ex) << 23);
    }
    const float wA = fexp2(eA * LOG2E);
    u = combine_swap<16>(tree16(u, EA)) * wA;
    endB = true;
  }

  // unlabeled: ln2 * logsumexp2_j(alpha~_j + T~[j][end]); each j appears 2x -> -1
  const int elab = endB ? labB : labA;
  const float alpha = ls + flog2(u);
  float v = alpha + Tld[elab * NL + 30];
  float mm = v;
  #pragma unroll
  for (int w = 32; w; w >>= 1) mm = fmaxf(mm, __shfl_xor(mm, w));
  float ss = fexp2(v - mm);
  #pragma unroll
  for (int w = 32; w; w >>= 1) ss += __shfl_xor(ss, w);
  if (lane == 0) atomicAdd(out + 0, LN2 * (mm + flog2(ss) - 1.0f));

  // labeled score (scaled domain, *ln2 at end)
  const int* tb = tags + (size_t)b * NS;
  float lab = 0.0f;
  if (lane == 0) {
    const int tg0 = tb[0];
    lab += Tld[31 * NL + tg0] + LOG2E * sb[tg0];   // begin
    const int tgl = tb[len - 1];
    lab += Tld[tgl * NL + 30];                     // end
  }
  for (int t2 = 1 + lane; t2 < len; t2 += 64) {
    const int tp = tb[t2 - 1];
    const int tg = tb[t2];
    lab += Tld[tp * NL + tg] + LOG2E * sb[(size_t)t2 * NL + tg];
  }
  #pragma unroll
  for (int w = 32; w; w >>= 1) lab += __shfl_xor(lab, w);
  if (lane == 0) atomicAdd(out + 1, LN2 * lab);
#undef STAGE
}

extern "C" void kernel_launch(void* const* d_in, const int* in_sizes, int n_in,
                              void* d_out, int out_size, void* d_ws, size_t ws_size,
                              hipStream_t stream) {
  const float* scores = (const float*)d_in[0];
  const float* trans  = (const float*)d_in[1];
  const int*   lens   = (const int*)d_in[2];
  const int*   tags   = (const int*)d_in[3];
  float* out = (float*)d_out;

  zero_out_k<<<1, 64, 0, stream>>>(out);
  crf_fwd<<<NB, 64, 0, stream>>>(scores, trans, lens, tags, out);
}